// Round 19
// baseline (134.954 us; speedup 1.0000x reference)
//
#include <hip/hip_runtime.h>
#include <math.h>

// Problem constants: B=2, S=T=2048, E=1024, H=16, D=64
typedef __attribute__((ext_vector_type(8))) short short8;
typedef __attribute__((ext_vector_type(4))) float f32x4;
typedef __attribute__((ext_vector_type(16))) float f32x16;
typedef unsigned short u16;

// fp32 -> bf16 round-to-nearest-even (finite inputs)
__device__ __forceinline__ u16 f2bf(float x) {
    unsigned int u = __float_as_uint(x);
    u += 0x7FFFu + ((u >> 16) & 1u);
    return (u16)(u >> 16);
}

// packed fp32x2 -> bf16x2, single instruction; no builtin on gfx950
__device__ __forceinline__ unsigned cvt_pk_bf16(float lo, float hi) {
    unsigned r;
    asm("v_cvt_pk_bf16_f32 %0, %1, %2" : "=v"(r) : "v"(lo), "v"(hi));
    return r;
}

__device__ __forceinline__ float max3f(float a, float b, float c) {
    float r;
    asm("v_max3_f32 %0, %1, %2, %3" : "=v"(r) : "v"(a), "v"(b), "v"(c));
    return r;
}

__device__ __forceinline__ void load_lds16(const void* g, void* l) {
    __builtin_amdgcn_global_load_lds(
        (const __attribute__((address_space(1))) unsigned int*)g,
        (__attribute__((address_space(3))) unsigned int*)l,
        16, 0, 0);
}

// ---------------------------------------------------------------------------
// Batched fp32 -> bf16 convert: weights only (4 tensors, ~24 MB, ~4.5 us).
// ---------------------------------------------------------------------------
struct CvtArgs {
    const float* src[4];
    u16* dst[4];
    int n8[4];
};

__global__ __launch_bounds__(256) void cvt_bf16(CvtArgs c) {
    const int z = blockIdx.z;
    const int i = blockIdx.x * 256 + threadIdx.x;
    if (i >= c.n8[z]) return;
    const float4* s = (const float4*)c.src[z];
    const float4 a = s[2 * i];
    const float4 b = s[2 * i + 1];
    union { short8 v; unsigned u[4]; } o;
    o.u[0] = cvt_pk_bf16(a.x, a.y);
    o.u[1] = cvt_pk_bf16(a.z, a.w);
    o.u[2] = cvt_pk_bf16(b.x, b.y);
    o.u[3] = cvt_pk_bf16(b.z, b.w);
    ((short8*)c.dst[z])[i] = o.v;
}

// ---------------------------------------------------------------------------
// QKV GEMM, 64x128 tile (M x N): A = raw fp32 activation (global_load_lds,
// chunk-XOR pre-swizzled source, post-ds_read cvt_pk -> bf16), W = bf16.
// Double-buffered, counted vmcnt(4). 512 blocks/z -> 6 blocks/CU.
// trans=0: C[token][dim] bf16 ; trans=1: C^T -> [b][dim][token] bf16.
// ---------------------------------------------------------------------------
struct GemmArgsF {
    const float* A[3];
    const u16* W[3];
    const float* bias[3];
    u16* C[3];
    float scale[3];
    int trans[3];
};

__global__ __launch_bounds__(256) void gemm_nt_af32(GemmArgsF ga, int M, int N, int K)
{
    __shared__ float As[2][64 * 32];    // fp32 A tile (64 rows x 32 k), swizzled
    __shared__ u16   Bs[2][128 * 32];   // bf16 W tile (128 rows x 32 k), linear
    const int z = blockIdx.z;
    const float* __restrict__ A = ga.A[z];
    const u16* __restrict__ W = ga.W[z];
    const float* __restrict__ bias = ga.bias[z];
    const float scale = ga.scale[z];
    const int trans = ga.trans[z];

    const int tid = threadIdx.x;
    const int w = tid >> 6, l = tid & 63;
    const int l4 = l >> 4, lm = l & 15;
    const int wr = w >> 1, wc = w & 1;   // wave tile: 32 rows x 64 cols

    // XCD decode for 512 blocks: each XCD owns 8 contiguous M-tiles
    const int idx = blockIdx.x;
    const int xcd = idx & 7;
    const int sl  = idx >> 3;            // 0..63
    const int bm = (xcd * 8 + (sl & 7)) * 64;   // token side (M=4096 -> 64 tiles)
    const int bn = (sl >> 3) * 128;             // dim side (N=1024 -> 8 tiles)

    // B staging geometry: blk covers 16 rows of 64 B
    const int srow = l >> 2;
    const int sseg = l & 3;
    // A staging geometry: blk covers 8 rows of 128 B, pre-swizzled source chunk
    const int arowi = l >> 3;
    const int achunk = (l & 7) ^ (arowi & 7);

    f32x4 acc[2][4];
#pragma unroll
    for (int m = 0; m < 2; ++m)
#pragma unroll
        for (int n = 0; n < 4; ++n) acc[m][n] = (f32x4){0.f, 0.f, 0.f, 0.f};

    auto stage = [&](int k0, int bi) {
        // A: 8 KB = 8 wave-issues of 1 KB (2 per wave)
#pragma unroll
        for (int ii = 0; ii < 2; ++ii) {
            const int blk = w * 2 + ii;            // 0..7
            const int row = blk * 8 + arowi;       // 0..63
            load_lds16(A + (size_t)(bm + row) * K + k0 + achunk * 4,
                       (char*)&As[bi][0] + blk * 1024);
        }
        // B: 8 KB = 8 wave-issues (2 per wave)
#pragma unroll
        for (int i = 0; i < 2; ++i) {
            const int blk = w * 2 + i;
            const int row = blk * 16 + srow;
            load_lds16(W + (size_t)(bn + row) * K + k0 + sseg * 8,
                       (char*)&Bs[bi][0] + blk * 1024);
        }
    };

    const int nIt = K / 32;
    stage(0, 0);

    for (int it = 0; it < nIt; ++it) {
        const int buf = it & 1;
        if (it < nIt - 1) {
            stage((it + 1) * 32, buf ^ 1);
            asm volatile("s_waitcnt vmcnt(4)" ::: "memory");  // tile it resident
        } else {
            asm volatile("s_waitcnt vmcnt(0)" ::: "memory");
        }
        __builtin_amdgcn_s_barrier();

        short8 af[2];
#pragma unroll
        for (int m = 0; m < 2; ++m) {
            const int arow = wr * 32 + m * 16 + lm;
            const f32x4 a0 = *(const f32x4*)&As[buf][arow * 32 + (((2 * l4)     ^ (arow & 7)) << 2)];
            const f32x4 a1 = *(const f32x4*)&As[buf][arow * 32 + (((2 * l4 + 1) ^ (arow & 7)) << 2)];
            union { short8 v; unsigned u[4]; } o;
            o.u[0] = cvt_pk_bf16(a0.x, a0.y);
            o.u[1] = cvt_pk_bf16(a0.z, a0.w);
            o.u[2] = cvt_pk_bf16(a1.x, a1.y);
            o.u[3] = cvt_pk_bf16(a1.z, a1.w);
            af[m] = o.v;
        }
        short8 bf[4];
#pragma unroll
        for (int n = 0; n < 4; ++n)
            bf[n] = *(const short8*)&Bs[buf][(wc * 64 + n * 16 + lm) * 32 + l4 * 8];

        __builtin_amdgcn_s_setprio(1);
#pragma unroll
        for (int m = 0; m < 2; ++m)
#pragma unroll
            for (int n = 0; n < 4; ++n)
                acc[m][n] = __builtin_amdgcn_mfma_f32_16x16x32_bf16(af[m], bf[n], acc[m][n], 0, 0, 0);
        __builtin_amdgcn_s_setprio(0);

        __builtin_amdgcn_s_barrier();
    }

    float bv[4];
#pragma unroll
    for (int n = 0; n < 4; ++n) bv[n] = bias[bn + wc * 64 + n * 16 + lm];

    if (!trans) {
#pragma unroll
        for (int m = 0; m < 2; ++m) {
#pragma unroll
            for (int n = 0; n < 4; ++n) {
                const int col = bn + wc * 64 + n * 16 + lm;
#pragma unroll
                for (int r = 0; r < 4; ++r) {
                    const int row = bm + wr * 32 + m * 16 + l4 * 4 + r;
                    ga.C[z][(size_t)row * N + col] = f2bf((acc[m][n][r] + bv[n]) * scale);
                }
            }
        }
    } else {
#pragma unroll
        for (int m = 0; m < 2; ++m) {
            const int tok = bm + wr * 32 + m * 16 + l4 * 4;   // +r, 4 consecutive
#pragma unroll
            for (int n = 0; n < 4; ++n) {
                const int dim = bn + wc * 64 + n * 16 + lm;
                const size_t base = (size_t)(tok >> 11) * 2097152
                                  + (size_t)dim * 2048 + (tok & 2047);
                ushort4 o;
                o.x = f2bf((acc[m][n][0] + bv[n]) * scale);
                o.y = f2bf((acc[m][n][1] + bv[n]) * scale);
                o.z = f2bf((acc[m][n][2] + bv[n]) * scale);
                o.w = f2bf((acc[m][n][3] + bv[n]) * scale);
                *(ushort4*)(ga.C[z] + base) = o;
            }
        }
    }
}

// ---------------------------------------------------------------------------
// Wo GEMM (bf16 x bf16 -> fp32), 64x128 tile, 512 blocks = 2 blocks/CU.
// dbuf + counted vmcnt(3).
// ---------------------------------------------------------------------------
struct GemmArgs {
    const u16* A;
    const u16* W;
    const float* bias;
    float* C;
};

__global__ __launch_bounds__(256) void gemm_nt_mfma(GemmArgs ga, int M, int N, int K)
{
    __shared__ u16 As[2][64 * 32];
    __shared__ u16 Bs[2][128 * 32];
    const u16* __restrict__ A = ga.A;
    const u16* __restrict__ W = ga.W;
    const float* __restrict__ bias = ga.bias;

    const int tid = threadIdx.x;
    const int w = tid >> 6, l = tid & 63;
    const int l4 = l >> 4, lm = l & 15;
    const int wr = w >> 1, wc = w & 1;

    const int idx = blockIdx.x;
    const int xcd = idx & 7;
    const int sl  = idx >> 3;
    const int bm = (xcd * 8 + (sl & 7)) * 64;
    const int bn = (sl >> 3) * 128;

    const int srow = l >> 2;
    const int sseg = l & 3;

    f32x4 acc[2][4];
#pragma unroll
    for (int m = 0; m < 2; ++m)
#pragma unroll
        for (int n = 0; n < 4; ++n) acc[m][n] = (f32x4){0.f, 0.f, 0.f, 0.f};

    auto stage = [&](int k0, int bi) {
        // A: 4 KB = 4 wave-issues (1 per wave); blk = w covers rows w*16..+15
        {
            const int row = w * 16 + srow;
            load_lds16(A + (size_t)(bm + row) * K + k0 + sseg * 8,
                       (char*)&As[bi][0] + w * 1024);
        }
        // B: 8 KB = 2 per wave
#pragma unroll
        for (int i = 0; i < 2; ++i) {
            const int blk = w * 2 + i;
            const int row = blk * 16 + srow;
            load_lds16(W + (size_t)(bn + row) * K + k0 + sseg * 8,
                       (char*)&Bs[bi][0] + blk * 1024);
        }
    };

    const int nIt = K / 32;
    stage(0, 0);

    for (int it = 0; it < nIt; ++it) {
        const int buf = it & 1;
        if (it < nIt - 1) {
            stage((it + 1) * 32, buf ^ 1);
            asm volatile("s_waitcnt vmcnt(3)" ::: "memory");
        } else {
            asm volatile("s_waitcnt vmcnt(0)" ::: "memory");
        }
        __builtin_amdgcn_s_barrier();

        short8 af[2], bf[4];
#pragma unroll
        for (int m = 0; m < 2; ++m)
            af[m] = *(const short8*)&As[buf][(wr * 32 + m * 16 + lm) * 32 + l4 * 8];
#pragma unroll
        for (int n = 0; n < 4; ++n)
            bf[n] = *(const short8*)&Bs[buf][(wc * 64 + n * 16 + lm) * 32 + l4 * 8];
#pragma unroll
        for (int m = 0; m < 2; ++m)
#pragma unroll
            for (int n = 0; n < 4; ++n)
                acc[m][n] = __builtin_amdgcn_mfma_f32_16x16x32_bf16(af[m], bf[n], acc[m][n], 0, 0, 0);

        __builtin_amdgcn_s_barrier();
    }

    float bv[4];
#pragma unroll
    for (int n = 0; n < 4; ++n) bv[n] = bias[bn + wc * 64 + n * 16 + lm];
#pragma unroll
    for (int m = 0; m < 2; ++m) {
#pragma unroll
        for (int n = 0; n < 4; ++n) {
            const int col = bn + wc * 64 + n * 16 + lm;
#pragma unroll
            for (int r = 0; r < 4; ++r) {
                const int row = bm + wr * 32 + m * 16 + l4 * 4 + r;
                ga.C[(size_t)row * N + col] = acc[m][n][r] + bv[n];
            }
        }
    }
}

// ---------------------------------------------------------------------------
// Flash attention v9b (R13/R16-verified, frozen).
// ---------------------------------------------------------------------------
__global__ __launch_bounds__(256, 2) void flash_attn_mfma9(
    const u16* __restrict__ Qb, const u16* __restrict__ Kb,
    const u16* __restrict__ Vt, u16* __restrict__ Ob)
{
    __shared__ u16 Ks[2][128 * 64];
    __shared__ u16 Vs[2][64 * 128];

    const int tid = threadIdx.x;
    const int w  = tid >> 6;
    const int l  = tid & 63;
    const int hi = l >> 5;
    const int lq = l & 31;

    const int id = blockIdx.x;
    const int xcd = id & 7;
    const int s = id >> 3;
    const int qt = s & 15;
    const int g0 = (s >> 4) * 8 + xcd;
    const int h = g0 & 15;
    const int b = g0 >> 4;
    const int qb0 = qt << 7;

    const size_t bbase = (size_t)b * 2048 * 1024 + (size_t)h * 64;
    const size_t vbase = (size_t)b * 2097152 + (size_t)(h * 64) * 2048;

    short8 qf[4];
    {
        const u16* qrow = Qb + bbase + (size_t)(qb0 + w * 32 + lq) * 1024;
#pragma unroll
        for (int t = 0; t < 4; ++t)
            qf[t] = *(const short8*)(qrow + t * 16 + hi * 8);
    }

    auto stageK = [&](int t0, int bufi) {
#pragma unroll
        for (int ii = 0; ii < 4; ++ii) {
            const int i = w * 4 + ii;
            const int key = i * 8 + (l >> 3);
            const int chunk = (l & 7) ^ ((l >> 3) & 7);
            load_lds16(Kb + bbase + (size_t)(t0 + key) * 1024 + chunk * 8,
                       (char*)&Ks[bufi][0] + i * 1024);
        }
    };
    auto stageV = [&](int t0, int bufi) {
#pragma unroll
        for (int ii = 0; ii < 4; ++ii) {
            const int i = w * 4 + ii;
            const int d = i * 4 + (l >> 4);
            const int chunk = (l & 15) ^ (d & 7);
            load_lds16(Vt + vbase + (size_t)d * 2048 + t0 + chunk * 8,
                       (char*)&Vs[bufi][0] + i * 1024);
        }
    };

    f32x16 oacc[2] = {{}, {}};
    float m_run = -1e30f;
    float l_run = 0.f;

    stageK(0, 0);
    stageV(0, 0);

    for (int t = 0; t < 16; ++t) {
        const int buf = t & 1;
        if (t < 15) {
            stageK((t + 1) * 128, buf ^ 1);
            stageV((t + 1) * 128, buf ^ 1);
            asm volatile("s_waitcnt vmcnt(8)" ::: "memory");
        } else {
            asm volatile("s_waitcnt vmcnt(0)" ::: "memory");
        }
        __builtin_amdgcn_s_barrier();

        f32x16 sacc[4] = {{}, {}, {}, {}};
        __builtin_amdgcn_s_setprio(1);
#pragma unroll
        for (int kb = 0; kb < 4; ++kb) {
#pragma unroll
            for (int tt = 0; tt < 4; ++tt) {
                const short8 kf = *(const short8*)
                    &Ks[buf][(32 * kb + lq) * 64 + (((2 * tt + hi) ^ (l & 7)) << 3)];
                sacc[kb] = __builtin_amdgcn_mfma_f32_32x32x16_bf16(kf, qf[tt], sacc[kb], 0, 0, 0);
            }
        }
        __builtin_amdgcn_s_setprio(0);

        float amax[4];
#pragma unroll
        for (int kb = 0; kb < 4; ++kb) {
            const f32x16 sv = sacc[kb];
            float t0 = max3f(sv[0], sv[1], sv[2]);
            float t1 = max3f(sv[3], sv[4], sv[5]);
            float t2 = max3f(sv[6], sv[7], sv[8]);
            float t3 = max3f(sv[9], sv[10], sv[11]);
            float t4 = max3f(sv[12], sv[13], sv[14]);
            float u0 = max3f(t0, t1, t2);
            float u1 = max3f(t3, t4, sv[15]);
            amax[kb] = fmaxf(u0, u1);
        }
        float mt = fmaxf(max3f(amax[0], amax[1], amax[2]), amax[3]);
        mt = fmaxf(mt, __shfl_xor(mt, 32));

        const bool resc = !__all(mt <= m_run + 8.0f);
        if (resc) {
            const float mn = fmaxf(m_run, mt);
            const float alpha = __builtin_amdgcn_exp2f(m_run - mn);
            m_run = mn;
            l_run *= alpha;
#pragma unroll
            for (int r = 0; r < 16; ++r) {
                const float a = __shfl(alpha, (r & 3) + 8 * (r >> 2) + 4 * hi);
                oacc[0][r] *= a;
                oacc[1][r] *= a;
            }
        }

        float lsum = 0.f;
        const float mr = m_run;
        unsigned wlo[4][4], whi[4][4];
#pragma unroll
        for (int kb = 0; kb < 4; ++kb) {
#pragma unroll
            for (int qd = 0; qd < 4; ++qd) {
                const float p0 = __builtin_amdgcn_exp2f(sacc[kb][4 * qd + 0] - mr);
                const float p1 = __builtin_amdgcn_exp2f(sacc[kb][4 * qd + 1] - mr);
                const float p2 = __builtin_amdgcn_exp2f(sacc[kb][4 * qd + 2] - mr);
                const float p3 = __builtin_amdgcn_exp2f(sacc[kb][4 * qd + 3] - mr);
                lsum += (p0 + p1) + (p2 + p3);
                wlo[kb][qd] = cvt_pk_bf16(p0, p1);
                whi[kb][qd] = cvt_pk_bf16(p2, p3);
            }
        }
        lsum += __shfl_xor(lsum, 32);
        l_run += lsum;

#pragma unroll
        for (int kb = 0; kb < 4; ++kb) {
#pragma unroll
            for (int u = 0; u < 2; ++u) {
                unsigned X  = wlo[kb][2 * u], Y  = wlo[kb][2 * u + 1];
                unsigned X2 = whi[kb][2 * u], Y2 = whi[kb][2 * u + 1];
                asm("v_permlane32_swap_b32 %0, %1" : "+v"(X),  "+v"(Y));
                asm("v_permlane32_swap_b32 %0, %1" : "+v"(X2), "+v"(Y2));
                union { unsigned u4[4]; short8 v8; } pa;
                pa.u4[0] = X; pa.u4[1] = X2; pa.u4[2] = Y; pa.u4[3] = Y2;
                const int sstep = 2 * kb + u;
                __builtin_amdgcn_s_setprio(1);
#pragma unroll
                for (int g = 0; g < 2; ++g) {
                    const int d = 32 * g + lq;
                    const short8 vf = *(const short8*)
                        &Vs[buf][d * 128 + (((2 * sstep + hi) ^ (d & 7)) << 3)];
                    oacc[g] = __builtin_amdgcn_mfma_f32_32x32x16_bf16(pa.v8, vf, oacc[g], 0, 0, 0);
                }
                __builtin_amdgcn_s_setprio(0);
            }
        }

        __builtin_amdgcn_s_barrier();
    }

#pragma unroll
    for (int r = 0; r < 16; ++r) {
        const int row = (r & 3) + 8 * (r >> 2) + 4 * hi;
        const float linv = 1.f / __shfl(l_run, row);
        const size_t orow = bbase + (size_t)(qb0 + w * 32 + row) * 1024;
        Ob[orow + lq]      = f2bf(oacc[0][r] * linv);
        Ob[orow + 32 + lq] = f2bf(oacc[1][r] * linv);
    }
}

extern "C" void kernel_launch(void* const* d_in, const int* in_sizes, int n_in,
                              void* d_out, int out_size, void* d_ws, size_t ws_size,
                              hipStream_t stream)
{
    const float* query = (const float*)d_in[0];
    const float* value = (const float*)d_in[1];
    const float* key   = (const float*)d_in[2];
    const float* Wq = (const float*)d_in[3];
    const float* bq = (const float*)d_in[4];
    const float* Wk = (const float*)d_in[5];
    const float* bk = (const float*)d_in[6];
    const float* Wv = (const float*)d_in[7];
    const float* bv = (const float*)d_in[8];
    const float* Wo = (const float*)d_in[9];
    const float* bo = (const float*)d_in[10];
    float* out = (float*)d_out;

    const int M = 2 * 2048;
    const int E = 1024;
    const size_t act = (size_t)M * E;
    const size_t wel = (size_t)E * E;

    u16* wqb = (u16*)d_ws;
    u16* wkb = wqb + wel;
    u16* wvb = wkb + wel;
    u16* wob = wvb + wel;
    u16* Qb  = wob + wel;
    u16* Kb  = Qb + act;
    u16* Vtb = Kb + act;   // V^T in [B, E, T] layout
    u16* Ab  = Vtb + act;

    // weights -> bf16 (24 MB, ~4.5 us)
    CvtArgs ca;
    ca.src[0] = Wq; ca.dst[0] = wqb; ca.n8[0] = (int)(wel / 8);
    ca.src[1] = Wk; ca.dst[1] = wkb; ca.n8[1] = (int)(wel / 8);
    ca.src[2] = Wv; ca.dst[2] = wvb; ca.n8[2] = (int)(wel / 8);
    ca.src[3] = Wo; ca.dst[3] = wob; ca.n8[3] = (int)(wel / 8);
    dim3 cgrid((unsigned)((wel / 8 + 255) / 256), 1, 4);
    hipLaunchKernelGGL(cvt_bf16, cgrid, dim3(256), 0, stream, ca);

    // q pre-scaled by (1/sqrt(D)) * log2(e): softmax runs on raw v_exp_f32
    const float SCALE_Q = 0.125f * 1.4426950408889634f;

    // QKV projections: raw fp32 activations, bf16 weights; z=2 stores V^T
    GemmArgsF gq;
    gq.A[0] = query; gq.W[0] = wqb; gq.bias[0] = bq; gq.C[0] = Qb;  gq.scale[0] = SCALE_Q; gq.trans[0] = 0;
    gq.A[1] = key;   gq.W[1] = wkb; gq.bias[1] = bk; gq.C[1] = Kb;  gq.scale[1] = 1.0f;    gq.trans[1] = 0;
    gq.A[2] = value; gq.W[2] = wvb; gq.bias[2] = bv; gq.C[2] = Vtb; gq.scale[2] = 1.0f;    gq.trans[2] = 1;
    hipLaunchKernelGGL(gemm_nt_af32, dim3(512, 1, 3), dim3(256), 0, stream, gq, M, E, E);

    // flash attention -> Ab (bf16), XCD-swizzled 1D grid
    hipLaunchKernelGGL(flash_attn_mfma9, dim3(512), dim3(256), 0, stream, Qb, Kb, Vtb, Ab);

    // output projection: bf16 GEMM, 64x128 tile, fp32 out
    GemmArgs go;
    go.A = Ab; go.W = wob; go.bias = bo; go.C = out;
    hipLaunchKernelGGL(gemm_nt_mfma, dim3(512), dim3(256), 0, stream, go, M, E, E);
}

// Round 20
// 123.098 us; speedup vs baseline: 1.0963x; 1.0963x over previous
//
#include <hip/hip_runtime.h>
#include <math.h>

// Problem constants: B=2, S=T=2048, E=1024, H=16, D=64
typedef __attribute__((ext_vector_type(8))) short short8;
typedef __attribute__((ext_vector_type(4))) float f32x4;
typedef __attribute__((ext_vector_type(16))) float f32x16;
typedef unsigned short u16;

// fp32 -> bf16 round-to-nearest-even (finite inputs)
__device__ __forceinline__ u16 f2bf(float x) {
    unsigned int u = __float_as_uint(x);
    u += 0x7FFFu + ((u >> 16) & 1u);
    return (u16)(u >> 16);
}

// packed fp32x2 -> bf16x2, single instruction; no builtin on gfx950
__device__ __forceinline__ unsigned cvt_pk_bf16(float lo, float hi) {
    unsigned r;
    asm("v_cvt_pk_bf16_f32 %0, %1, %2" : "=v"(r) : "v"(lo), "v"(hi));
    return r;
}

__device__ __forceinline__ float max3f(float a, float b, float c) {
    float r;
    asm("v_max3_f32 %0, %1, %2, %3" : "=v"(r) : "v"(a), "v"(b), "v"(c));
    return r;
}

__device__ __forceinline__ void load_lds16(const void* g, void* l) {
    __builtin_amdgcn_global_load_lds(
        (const __attribute__((address_space(1))) unsigned int*)g,
        (__attribute__((address_space(3))) unsigned int*)l,
        16, 0, 0);
}

// ---------------------------------------------------------------------------
// Batched fp32 -> bf16 convert: WEIGHTS ONLY (4 tensors, ~24 MB, ~4.5 us).
// ---------------------------------------------------------------------------
struct CvtArgs {
    const float* src[4];
    u16* dst[4];
    int n8[4];
};

__global__ __launch_bounds__(256) void cvt_bf16(CvtArgs c) {
    const int z = blockIdx.z;
    const int i = blockIdx.x * 256 + threadIdx.x;
    if (i >= c.n8[z]) return;
    const float4* s = (const float4*)c.src[z];
    const float4 a = s[2 * i];
    const float4 b = s[2 * i + 1];
    union { short8 v; unsigned u[4]; } o;
    o.u[0] = cvt_pk_bf16(a.x, a.y);
    o.u[1] = cvt_pk_bf16(a.z, a.w);
    o.u[2] = cvt_pk_bf16(b.x, b.y);
    o.u[3] = cvt_pk_bf16(b.z, b.w);
    ((short8*)c.dst[z])[i] = o.v;
}

// ---------------------------------------------------------------------------
// QKV GEMM (R18-verified): 128x128 tile, A = raw fp32 activation staged via
// global_load_lds with chunk-XOR pre-swizzled source; converted to bf16
// AFTER ds_read via cvt_pk. B staged bf16. Double-buffered, counted vmcnt(6).
//   trans=0: C[token][dim] bf16      trans=1: C^T -> [b][dim][token] bf16
// 1D grid, XCD-aware decode (R9-verified).
// ---------------------------------------------------------------------------
struct GemmArgsF {
    const float* A[3];
    const u16* W[3];
    const float* bias[3];
    u16* C[3];
    float scale[3];
    int trans[3];
};

__global__ __launch_bounds__(256) void gemm_nt_af32(GemmArgsF ga, int M, int N, int K)
{
    __shared__ float As[2][128 * 32];   // fp32 A tile, chunk-swizzled
    __shared__ u16   Bs[2][128 * 32];   // bf16 W tile, linear (R13)
    const int z = blockIdx.z;
    const float* __restrict__ A = ga.A[z];
    const u16* __restrict__ W = ga.W[z];
    const float* __restrict__ bias = ga.bias[z];
    const float scale = ga.scale[z];
    const int trans = ga.trans[z];

    const int tid = threadIdx.x;
    const int w = tid >> 6, l = tid & 63;
    const int l4 = l >> 4, lm = l & 15;
    const int wr = w >> 1, wc = w & 1;

    const int idx = blockIdx.x;
    const int xcd = idx & 7;
    const int sl  = idx >> 3;
    const int bmi = xcd * 4 + (sl & 3);
    const int bni = sl >> 2;
    const int bm = bmi * 128;   // token side (M)
    const int bn = bni * 128;   // dim side (N)

    const int srow = l >> 2;
    const int sseg = l & 3;
    const int arowi = l >> 3;
    const int achunk = (l & 7) ^ (arowi & 7);

    f32x4 acc[4][4];
#pragma unroll
    for (int m = 0; m < 4; ++m)
#pragma unroll
        for (int n = 0; n < 4; ++n) acc[m][n] = (f32x4){0.f, 0.f, 0.f, 0.f};

    auto stage = [&](int k0, int bi) {
#pragma unroll
        for (int ii = 0; ii < 4; ++ii) {
            const int blk = w * 4 + ii;
            const int row = blk * 8 + arowi;
            load_lds16(A + (size_t)(bm + row) * K + k0 + achunk * 4,
                       (char*)&As[bi][0] + blk * 1024);
        }
#pragma unroll
        for (int i = 0; i < 2; ++i) {
            const int blk = w * 2 + i;
            const int row = blk * 16 + srow;
            load_lds16(W + (size_t)(bn + row) * K + k0 + sseg * 8,
                       (char*)&Bs[bi][0] + blk * 1024);
        }
    };

    const int nIt = K / 32;
    stage(0, 0);

    for (int it = 0; it < nIt; ++it) {
        const int buf = it & 1;
        if (it < nIt - 1) {
            stage((it + 1) * 32, buf ^ 1);
            asm volatile("s_waitcnt vmcnt(6)" ::: "memory");
        } else {
            asm volatile("s_waitcnt vmcnt(0)" ::: "memory");
        }
        __builtin_amdgcn_s_barrier();

        short8 af[4];
#pragma unroll
        for (int m = 0; m < 4; ++m) {
            const int arow = wr * 64 + m * 16 + lm;
            const f32x4 a0 = *(const f32x4*)&As[buf][arow * 32 + (((2 * l4)     ^ (arow & 7)) << 2)];
            const f32x4 a1 = *(const f32x4*)&As[buf][arow * 32 + (((2 * l4 + 1) ^ (arow & 7)) << 2)];
            union { short8 v; unsigned u[4]; } o;
            o.u[0] = cvt_pk_bf16(a0.x, a0.y);
            o.u[1] = cvt_pk_bf16(a0.z, a0.w);
            o.u[2] = cvt_pk_bf16(a1.x, a1.y);
            o.u[3] = cvt_pk_bf16(a1.z, a1.w);
            af[m] = o.v;
        }
        short8 bf[4];
#pragma unroll
        for (int n = 0; n < 4; ++n)
            bf[n] = *(const short8*)&Bs[buf][(wc * 64 + n * 16 + lm) * 32 + l4 * 8];

        __builtin_amdgcn_s_setprio(1);
#pragma unroll
        for (int m = 0; m < 4; ++m)
#pragma unroll
            for (int n = 0; n < 4; ++n)
                acc[m][n] = __builtin_amdgcn_mfma_f32_16x16x32_bf16(af[m], bf[n], acc[m][n], 0, 0, 0);
        __builtin_amdgcn_s_setprio(0);

        __builtin_amdgcn_s_barrier();
    }

    float bv[4];
#pragma unroll
    for (int n = 0; n < 4; ++n) bv[n] = bias[bn + wc * 64 + n * 16 + lm];

    if (!trans) {
#pragma unroll
        for (int m = 0; m < 4; ++m) {
#pragma unroll
            for (int n = 0; n < 4; ++n) {
                const int col = bn + wc * 64 + n * 16 + lm;
#pragma unroll
                for (int r = 0; r < 4; ++r) {
                    const int row = bm + wr * 64 + m * 16 + l4 * 4 + r;
                    ga.C[z][(size_t)row * N + col] = f2bf((acc[m][n][r] + bv[n]) * scale);
                }
            }
        }
    } else {
#pragma unroll
        for (int m = 0; m < 4; ++m) {
            const int tok = bm + wr * 64 + m * 16 + l4 * 4;
#pragma unroll
            for (int n = 0; n < 4; ++n) {
                const int dim = bn + wc * 64 + n * 16 + lm;
                const size_t base = (size_t)(tok >> 11) * 2097152
                                  + (size_t)dim * 2048 + (tok & 2047);
                ushort4 o;
                o.x = f2bf((acc[m][n][0] + bv[n]) * scale);
                o.y = f2bf((acc[m][n][1] + bv[n]) * scale);
                o.z = f2bf((acc[m][n][2] + bv[n]) * scale);
                o.w = f2bf((acc[m][n][3] + bv[n]) * scale);
                *(ushort4*)(ga.C[z] + base) = o;
            }
        }
    }
}

// ---------------------------------------------------------------------------
// Wo GEMM (R13-verified): bf16 x bf16 -> fp32, 128x128 tile, dbuf + vmcnt(4).
// ---------------------------------------------------------------------------
struct GemmArgs {
    const u16* A;
    const u16* W;
    const float* bias;
    float* C;
};

__global__ __launch_bounds__(256) void gemm_nt_mfma(GemmArgs ga, int M, int N, int K)
{
    __shared__ u16 As[2][128 * 32];
    __shared__ u16 Bs[2][128 * 32];
    const u16* __restrict__ A = ga.A;
    const u16* __restrict__ W = ga.W;
    const float* __restrict__ bias = ga.bias;

    const int tid = threadIdx.x;
    const int w = tid >> 6, l = tid & 63;
    const int l4 = l >> 4, lm = l & 15;
    const int wr = w >> 1, wc = w & 1;

    const int idx = blockIdx.x;
    const int xcd = idx & 7;
    const int sl  = idx >> 3;
    const int bm = (xcd * 4 + (sl & 3)) * 128;
    const int bn = (sl >> 2) * 128;

    const int srow = l >> 2;
    const int sseg = l & 3;

    f32x4 acc[4][4];
#pragma unroll
    for (int m = 0; m < 4; ++m)
#pragma unroll
        for (int n = 0; n < 4; ++n) acc[m][n] = (f32x4){0.f, 0.f, 0.f, 0.f};

    auto stage = [&](int k0, int bi) {
#pragma unroll
        for (int i = 0; i < 2; ++i) {
            const int blk = w * 2 + i;
            const int row = blk * 16 + srow;
            load_lds16(A + (size_t)(bm + row) * K + k0 + sseg * 8,
                       (char*)&As[bi][0] + blk * 1024);
            load_lds16(W + (size_t)(bn + row) * K + k0 + sseg * 8,
                       (char*)&Bs[bi][0] + blk * 1024);
        }
    };

    const int nIt = K / 32;
    stage(0, 0);

    for (int it = 0; it < nIt; ++it) {
        const int buf = it & 1;
        if (it < nIt - 1) {
            stage((it + 1) * 32, buf ^ 1);
            asm volatile("s_waitcnt vmcnt(4)" ::: "memory");
        } else {
            asm volatile("s_waitcnt vmcnt(0)" ::: "memory");
        }
        __builtin_amdgcn_s_barrier();

        short8 af[4], bf[4];
#pragma unroll
        for (int m = 0; m < 4; ++m)
            af[m] = *(const short8*)&As[buf][(wr * 64 + m * 16 + lm) * 32 + l4 * 8];
#pragma unroll
        for (int n = 0; n < 4; ++n)
            bf[n] = *(const short8*)&Bs[buf][(wc * 64 + n * 16 + lm) * 32 + l4 * 8];
#pragma unroll
        for (int m = 0; m < 4; ++m)
#pragma unroll
            for (int n = 0; n < 4; ++n)
                acc[m][n] = __builtin_amdgcn_mfma_f32_16x16x32_bf16(af[m], bf[n], acc[m][n], 0, 0, 0);

        __builtin_amdgcn_s_barrier();
    }

    float bv[4];
#pragma unroll
    for (int n = 0; n < 4; ++n) bv[n] = bias[bn + wc * 64 + n * 16 + lm];
#pragma unroll
    for (int m = 0; m < 4; ++m) {
#pragma unroll
        for (int n = 0; n < 4; ++n) {
            const int col = bn + wc * 64 + n * 16 + lm;
#pragma unroll
            for (int r = 0; r < 4; ++r) {
                const int row = bm + wr * 64 + m * 16 + l4 * 4 + r;
                ga.C[(size_t)row * N + col] = acc[m][n][r] + bv[n];
            }
        }
    }
}

// ---------------------------------------------------------------------------
// Flash attention v9b (R13/R16-verified, frozen).
// ---------------------------------------------------------------------------
__global__ __launch_bounds__(256, 2) void flash_attn_mfma9(
    const u16* __restrict__ Qb, const u16* __restrict__ Kb,
    const u16* __restrict__ Vt, u16* __restrict__ Ob)
{
    __shared__ u16 Ks[2][128 * 64];
    __shared__ u16 Vs[2][64 * 128];

    const int tid = threadIdx.x;
    const int w  = tid >> 6;
    const int l  = tid & 63;
    const int hi = l >> 5;
    const int lq = l & 31;

    const int id = blockIdx.x;
    const int xcd = id & 7;
    const int s = id >> 3;
    const int qt = s & 15;
    const int g0 = (s >> 4) * 8 + xcd;
    const int h = g0 & 15;
    const int b = g0 >> 4;
    const int qb0 = qt << 7;

    const size_t bbase = (size_t)b * 2048 * 1024 + (size_t)h * 64;
    const size_t vbase = (size_t)b * 2097152 + (size_t)(h * 64) * 2048;

    short8 qf[4];
    {
        const u16* qrow = Qb + bbase + (size_t)(qb0 + w * 32 + lq) * 1024;
#pragma unroll
        for (int t = 0; t < 4; ++t)
            qf[t] = *(const short8*)(qrow + t * 16 + hi * 8);
    }

    auto stageK = [&](int t0, int bufi) {
#pragma unroll
        for (int ii = 0; ii < 4; ++ii) {
            const int i = w * 4 + ii;
            const int key = i * 8 + (l >> 3);
            const int chunk = (l & 7) ^ ((l >> 3) & 7);
            load_lds16(Kb + bbase + (size_t)(t0 + key) * 1024 + chunk * 8,
                       (char*)&Ks[bufi][0] + i * 1024);
        }
    };
    auto stageV = [&](int t0, int bufi) {
#pragma unroll
        for (int ii = 0; ii < 4; ++ii) {
            const int i = w * 4 + ii;
            const int d = i * 4 + (l >> 4);
            const int chunk = (l & 15) ^ (d & 7);
            load_lds16(Vt + vbase + (size_t)d * 2048 + t0 + chunk * 8,
                       (char*)&Vs[bufi][0] + i * 1024);
        }
    };

    f32x16 oacc[2] = {{}, {}};
    float m_run = -1e30f;
    float l_run = 0.f;

    stageK(0, 0);
    stageV(0, 0);

    for (int t = 0; t < 16; ++t) {
        const int buf = t & 1;
        if (t < 15) {
            stageK((t + 1) * 128, buf ^ 1);
            stageV((t + 1) * 128, buf ^ 1);
            asm volatile("s_waitcnt vmcnt(8)" ::: "memory");
        } else {
            asm volatile("s_waitcnt vmcnt(0)" ::: "memory");
        }
        __builtin_amdgcn_s_barrier();

        f32x16 sacc[4] = {{}, {}, {}, {}};
        __builtin_amdgcn_s_setprio(1);
#pragma unroll
        for (int kb = 0; kb < 4; ++kb) {
#pragma unroll
            for (int tt = 0; tt < 4; ++tt) {
                const short8 kf = *(const short8*)
                    &Ks[buf][(32 * kb + lq) * 64 + (((2 * tt + hi) ^ (l & 7)) << 3)];
                sacc[kb] = __builtin_amdgcn_mfma_f32_32x32x16_bf16(kf, qf[tt], sacc[kb], 0, 0, 0);
            }
        }
        __builtin_amdgcn_s_setprio(0);

        float amax[4];
#pragma unroll
        for (int kb = 0; kb < 4; ++kb) {
            const f32x16 sv = sacc[kb];
            float t0 = max3f(sv[0], sv[1], sv[2]);
            float t1 = max3f(sv[3], sv[4], sv[5]);
            float t2 = max3f(sv[6], sv[7], sv[8]);
            float t3 = max3f(sv[9], sv[10], sv[11]);
            float t4 = max3f(sv[12], sv[13], sv[14]);
            float u0 = max3f(t0, t1, t2);
            float u1 = max3f(t3, t4, sv[15]);
            amax[kb] = fmaxf(u0, u1);
        }
        float mt = fmaxf(max3f(amax[0], amax[1], amax[2]), amax[3]);
        mt = fmaxf(mt, __shfl_xor(mt, 32));

        const bool resc = !__all(mt <= m_run + 8.0f);
        if (resc) {
            const float mn = fmaxf(m_run, mt);
            const float alpha = __builtin_amdgcn_exp2f(m_run - mn);
            m_run = mn;
            l_run *= alpha;
#pragma unroll
            for (int r = 0; r < 16; ++r) {
                const float a = __shfl(alpha, (r & 3) + 8 * (r >> 2) + 4 * hi);
                oacc[0][r] *= a;
                oacc[1][r] *= a;
            }
        }

        float lsum = 0.f;
        const float mr = m_run;
        unsigned wlo[4][4], whi[4][4];
#pragma unroll
        for (int kb = 0; kb < 4; ++kb) {
#pragma unroll
            for (int qd = 0; qd < 4; ++qd) {
                const float p0 = __builtin_amdgcn_exp2f(sacc[kb][4 * qd + 0] - mr);
                const float p1 = __builtin_amdgcn_exp2f(sacc[kb][4 * qd + 1] - mr);
                const float p2 = __builtin_amdgcn_exp2f(sacc[kb][4 * qd + 2] - mr);
                const float p3 = __builtin_amdgcn_exp2f(sacc[kb][4 * qd + 3] - mr);
                lsum += (p0 + p1) + (p2 + p3);
                wlo[kb][qd] = cvt_pk_bf16(p0, p1);
                whi[kb][qd] = cvt_pk_bf16(p2, p3);
            }
        }
        lsum += __shfl_xor(lsum, 32);
        l_run += lsum;

#pragma unroll
        for (int kb = 0; kb < 4; ++kb) {
#pragma unroll
            for (int u = 0; u < 2; ++u) {
                unsigned X  = wlo[kb][2 * u], Y  = wlo[kb][2 * u + 1];
                unsigned X2 = whi[kb][2 * u], Y2 = whi[kb][2 * u + 1];
                asm("v_permlane32_swap_b32 %0, %1" : "+v"(X),  "+v"(Y));
                asm("v_permlane32_swap_b32 %0, %1" : "+v"(X2), "+v"(Y2));
                union { unsigned u4[4]; short8 v8; } pa;
                pa.u4[0] = X; pa.u4[1] = X2; pa.u4[2] = Y; pa.u4[3] = Y2;
                const int sstep = 2 * kb + u;
                __builtin_amdgcn_s_setprio(1);
#pragma unroll
                for (int g = 0; g < 2; ++g) {
                    const int d = 32 * g + lq;
                    const short8 vf = *(const short8*)
                        &Vs[buf][d * 128 + (((2 * sstep + hi) ^ (d & 7)) << 3)];
                    oacc[g] = __builtin_amdgcn_mfma_f32_32x32x16_bf16(pa.v8, vf, oacc[g], 0, 0, 0);
                }
                __builtin_amdgcn_s_setprio(0);
            }
        }

        __builtin_amdgcn_s_barrier();
    }

#pragma unroll
    for (int r = 0; r < 16; ++r) {
        const int row = (r & 3) + 8 * (r >> 2) + 4 * hi;
        const float linv = 1.f / __shfl(l_run, row);
        const size_t orow = bbase + (size_t)(qb0 + w * 32 + row) * 1024;
        Ob[orow + lq]      = f2bf(oacc[0][r] * linv);
        Ob[orow + 32 + lq] = f2bf(oacc[1][r] * linv);
    }
}

extern "C" void kernel_launch(void* const* d_in, const int* in_sizes, int n_in,
                              void* d_out, int out_size, void* d_ws, size_t ws_size,
                              hipStream_t stream)
{
    const float* query = (const float*)d_in[0];
    const float* value = (const float*)d_in[1];
    const float* key   = (const float*)d_in[2];
    const float* Wq = (const float*)d_in[3];
    const float* bq = (const float*)d_in[4];
    const float* Wk = (const float*)d_in[5];
    const float* bk = (const float*)d_in[6];
    const float* Wv = (const float*)d_in[7];
    const float* bv = (const float*)d_in[8];
    const float* Wo = (const float*)d_in[9];
    const float* bo = (const float*)d_in[10];
    float* out = (float*)d_out;

    const int M = 2 * 2048;
    const int E = 1024;
    const size_t act = (size_t)M * E;
    const size_t wel = (size_t)E * E;

    u16* wqb = (u16*)d_ws;
    u16* wkb = wqb + wel;
    u16* wvb = wkb + wel;
    u16* wob = wvb + wel;
    u16* Qb  = wob + wel;
    u16* Kb  = Qb + act;
    u16* Vtb = Kb + act;   // V^T in [B, E, T] layout
    u16* Ab  = Vtb + act;

    // weights -> bf16 (24 MB, ~4.5 us)
    CvtArgs ca;
    ca.src[0] = Wq; ca.dst[0] = wqb; ca.n8[0] = (int)(wel / 8);
    ca.src[1] = Wk; ca.dst[1] = wkb; ca.n8[1] = (int)(wel / 8);
    ca.src[2] = Wv; ca.dst[2] = wvb; ca.n8[2] = (int)(wel / 8);
    ca.src[3] = Wo; ca.dst[3] = wob; ca.n8[3] = (int)(wel / 8);
    dim3 cgrid((unsigned)((wel / 8 + 255) / 256), 1, 4);
    hipLaunchKernelGGL(cvt_bf16, cgrid, dim3(256), 0, stream, ca);

    // q pre-scaled by (1/sqrt(D)) * log2(e): softmax runs on raw v_exp_f32
    const float SCALE_Q = 0.125f * 1.4426950408889634f;

    // QKV projections: raw fp32 activations, bf16 weights; z=2 stores V^T
    GemmArgsF gq;
    gq.A[0] = query; gq.W[0] = wqb; gq.bias[0] = bq; gq.C[0] = Qb;  gq.scale[0] = SCALE_Q; gq.trans[0] = 0;
    gq.A[1] = key;   gq.W[1] = wkb; gq.bias[1] = bk; gq.C[1] = Kb;  gq.scale[1] = 1.0f;    gq.trans[1] = 0;
    gq.A[2] = value; gq.W[2] = wvb; gq.bias[2] = bv; gq.C[2] = Vtb; gq.scale[2] = 1.0f;    gq.trans[2] = 1;
    hipLaunchKernelGGL(gemm_nt_af32, dim3(256, 1, 3), dim3(256), 0, stream, gq, M, E, E);

    // flash attention -> Ab (bf16), XCD-swizzled 1D grid
    hipLaunchKernelGGL(flash_attn_mfma9, dim3(512), dim3(256), 0, stream, Qb, Kb, Vtb, Ab);

    // output projection: bf16 GEMM (R13 path), fp32 out
    GemmArgs go;
    go.A = Ab; go.W = wob; go.bias = bo; go.C = out;
    hipLaunchKernelGGL(gemm_nt_mfma, dim3(256), dim3(256), 0, stream, go, M, E, E);
}